// Round 15
// baseline (206.289 us; speedup 1.0000x reference)
//
#include <hip/hip_runtime.h>
#include <hip/hip_fp8.h>

#define IN_FEATS 256
#define HID 64
#define OUTF 32
#define JK (3*HID)

#define NB    128   // bucket slots (used: 98)
#define BSH   10    // bucket covers 1024 nodes
#define NBLK2 512   // edge-chunk blocks for hist/scatter (doubled: R14 showed scatter
                    // parallelism, not traffic, limits p3m; 32-edge runs = 1 line)
// NOTE: packed pairbuf assumes N <= 2^17 (src 17 bits, local dst 10 bits). N=100000.

typedef __attribute__((ext_vector_type(4))) float floatx4;
typedef __attribute__((ext_vector_type(8))) short shortx8;

__device__ inline unsigned short f2bf(float f) {
    unsigned u = __float_as_uint(f);
    unsigned r = (u + 0x7fffu + ((u >> 16) & 1u)) >> 16;
    return (unsigned short)r;
}
__device__ inline float bf2f(unsigned short u) {
    return __uint_as_float(((unsigned)u) << 16);
}
__device__ inline unsigned pack2(float a, float b) {
    return (unsigned)f2bf(a) | ((unsigned)f2bf(b) << 16);
}
// fp8 e4m3 (OCP on gfx950) helpers
__device__ inline unsigned char f2q(float f) {
    __hip_fp8_e4m3 q(f);
    return (unsigned char)q.__x;
}
__device__ inline float q2f(unsigned char b) {
    union { unsigned char c; __hip_fp8_e4m3 q; } u;
    u.c = b;
    return (float)u.q;
}
__device__ inline void accq8(uint2 u, float* a, float s) {
    a[0] = fmaf(q2f((unsigned char)(u.x      )), s, a[0]);
    a[1] = fmaf(q2f((unsigned char)(u.x >>  8)), s, a[1]);
    a[2] = fmaf(q2f((unsigned char)(u.x >> 16)), s, a[2]);
    a[3] = fmaf(q2f((unsigned char)(u.x >> 24)), s, a[3]);
    a[4] = fmaf(q2f((unsigned char)(u.y      )), s, a[4]);
    a[5] = fmaf(q2f((unsigned char)(u.y >>  8)), s, a[5]);
    a[6] = fmaf(q2f((unsigned char)(u.y >> 16)), s, a[6]);
    a[7] = fmaf(q2f((unsigned char)(u.y >> 24)), s, a[7]);
}
__device__ inline void acc8(uint4 u, float* a) {
    a[0] += bf2f((unsigned short)(u.x & 0xffff)); a[1] += bf2f((unsigned short)(u.x >> 16));
    a[2] += bf2f((unsigned short)(u.y & 0xffff)); a[3] += bf2f((unsigned short)(u.y >> 16));
    a[4] += bf2f((unsigned short)(u.z & 0xffff)); a[5] += bf2f((unsigned short)(u.z >> 16));
    a[6] += bf2f((unsigned short)(u.w & 0xffff)); a[7] += bf2f((unsigned short)(u.w >> 16));
}

// chunk bounds: cb multiple of 8 so int4-pair loads stay aligned from an aligned base
__device__ inline void chunk_bounds(int E, int b, int& beg, int& end) {
    int cb = ((E + NBLK2 - 1) / NBLK2 + 7) & ~7;
    beg = b * cb;
    end = min(beg + cb, E);
}

// ---------------- P1: per-block LDS histograms (8-edge unrolled) ----------------
__global__ __launch_bounds__(256) void p1_hist(const int* __restrict__ src,
                                               const int* __restrict__ dst, int E,
                                               int* __restrict__ bhd, int* __restrict__ bhs) {
    __shared__ int hd[NB], hs[NB];
    int b = blockIdx.x;
    for (int t = threadIdx.x; t < NB; t += 256) { hd[t] = 0; hs[t] = 0; }
    __syncthreads();
    int beg, end;
    chunk_bounds(E, b, beg, end);
    int e = beg + threadIdx.x * 8;
    for (; e + 8 <= end; e += 2048) {
        int4 d0 = *(const int4*)&dst[e];
        int4 d1 = *(const int4*)&dst[e + 4];
        int4 s0 = *(const int4*)&src[e];
        int4 s1 = *(const int4*)&src[e + 4];
        atomicAdd(&hd[d0.x >> BSH], 1); atomicAdd(&hd[d0.y >> BSH], 1);
        atomicAdd(&hd[d0.z >> BSH], 1); atomicAdd(&hd[d0.w >> BSH], 1);
        atomicAdd(&hd[d1.x >> BSH], 1); atomicAdd(&hd[d1.y >> BSH], 1);
        atomicAdd(&hd[d1.z >> BSH], 1); atomicAdd(&hd[d1.w >> BSH], 1);
        atomicAdd(&hs[s0.x >> BSH], 1); atomicAdd(&hs[s0.y >> BSH], 1);
        atomicAdd(&hs[s0.z >> BSH], 1); atomicAdd(&hs[s0.w >> BSH], 1);
        atomicAdd(&hs[s1.x >> BSH], 1); atomicAdd(&hs[s1.y >> BSH], 1);
        atomicAdd(&hs[s1.z >> BSH], 1); atomicAdd(&hs[s1.w >> BSH], 1);
    }
    for (; e < end; ++e) {
        atomicAdd(&hd[dst[e] >> BSH], 1);
        atomicAdd(&hs[src[e] >> BSH], 1);
    }
    __syncthreads();
    for (int t = threadIdx.x; t < NB; t += 256) {
        bhd[b * NB + t] = hd[t];
        bhs[b * NB + t] = hs[t];
    }
}

// ---------------- P2a (+wprep grid-fused) ----------------
__global__ __launch_bounds__(256) void p2a_tot(const int* __restrict__ bhd,
                                               const int* __restrict__ bhs,
                                               int* __restrict__ totd, int* __restrict__ tots,
                                               int nblk,
                                               const float* __restrict__ W1, const float* __restrict__ W2,
                                               const float* __restrict__ W3, const float* __restrict__ Wm,
                                               unsigned short* __restrict__ W1t, unsigned short* __restrict__ W2t,
                                               unsigned short* __restrict__ W3t, unsigned short* __restrict__ Wmt) {
    if ((int)blockIdx.x >= 2 * NB) {
        int i = (blockIdx.x - 2 * NB) * 256 + threadIdx.x;
        if (i < 256 * 64) { int k = i / 64, c = i % 64; W1t[c * 256 + k] = f2bf(W1[i]); return; }
        int j = i - 256 * 64;
        if (j < 64 * 64) { int k = j / 64, c = j % 64; W2t[c * 64 + k] = f2bf(W2[j]); return; }
        int j2 = j - 64 * 64;
        if (j2 < 64 * 64) { int k = j2 / 64, c = j2 % 64; W3t[c * 64 + k] = f2bf(W3[j2]); return; }
        int j3 = j2 - 64 * 64;
        if (j3 < 192 * 32) { int k = j3 / 32, c = j3 % 32; Wmt[c * 192 + k] = f2bf(Wm[j3]); }
        return;
    }
    __shared__ int s[256];
    int side = blockIdx.x >> 7;
    int t = blockIdx.x & (NB - 1);
    const int* bh = side ? bhs : bhd;
    int acc = 0;
    for (int k = threadIdx.x; k < nblk; k += 256) acc += bh[k * NB + t];
    s[threadIdx.x] = acc;
    __syncthreads();
    for (int off = 128; off > 0; off >>= 1) {
        if (threadIdx.x < off) s[threadIdx.x] += s[threadIdx.x + off];
        __syncthreads();
    }
    if (threadIdx.x == 0) (side ? tots : totd)[t] = s[0];
}

// ---------------- P2b: exclusive scan over NB bucket totals ----------------
__global__ __launch_bounds__(128) void p2b_scan(const int* __restrict__ totd,
                                                const int* __restrict__ tots,
                                                int* __restrict__ based, int* __restrict__ bases) {
    __shared__ int s[NB];
    const int* tot = blockIdx.x ? tots : totd;
    int* bb = blockIdx.x ? bases : based;
    int t = threadIdx.x;
    int v = tot[t];
    s[t] = v;
    __syncthreads();
    for (int off = 1; off < NB; off <<= 1) {
        int u = (t >= off) ? s[t - off] : 0;
        __syncthreads();
        s[t] += u;
        __syncthreads();
    }
    bb[t] = s[t] - v;
    if (t == NB - 1) bb[NB] = s[NB - 1];
}

// ---------------- P2c: per-bucket prefix over blocks (in place) ----------------
__global__ __launch_bounds__(256) void p2c_off(int* __restrict__ bhd, int* __restrict__ bhs,
                                               const int* __restrict__ based,
                                               const int* __restrict__ bases, int nblk) {
    __shared__ int s[256];
    int side = blockIdx.x >> 7;
    int t = blockIdx.x & (NB - 1);
    int* bh = side ? bhs : bhd;
    int carry = (side ? bases : based)[t];
    for (int k0 = 0; k0 < nblk; k0 += 256) {
        int k = k0 + threadIdx.x;
        int v = (k < nblk) ? bh[k * NB + t] : 0;
        s[threadIdx.x] = v;
        __syncthreads();
        for (int off = 1; off < 256; off <<= 1) {
            int u = (threadIdx.x >= off) ? s[threadIdx.x - off] : 0;
            __syncthreads();
            s[threadIdx.x] += u;
            __syncthreads();
        }
        if (k < nblk) bh[k * NB + t] = carry + s[threadIdx.x] - v;
        int tot = s[255];
        __syncthreads();
        carry += tot;
    }
}

// ---------------- P3M: grid-fused {dst-scatter} + {src-scatter} + {layer-1 GEMM} ----
// Scatter blocks FIRST (R13 lesson: small latency-bound role first, BW flood after).
__global__ __launch_bounds__(256) void p3m(
    const int* __restrict__ src, const int* __restrict__ dst, int E,
    const int* __restrict__ bhd, const int* __restrict__ bhs,
    int* __restrict__ pairbuf, int* __restrict__ srctmp,
    const float* __restrict__ feat, const unsigned short* __restrict__ W1t,
    unsigned char* __restrict__ outq, int nrows) {
    __shared__ int cur[NB];
    __shared__ unsigned short Al[64 * 64];
    __shared__ unsigned short Bl[64 * 64];

    if ((int)blockIdx.x < NBLK2) {
        // ---------- dst-pair partition (8-edge unrolled) ----------
        int b = blockIdx.x;
        for (int t = threadIdx.x; t < NB; t += 256) cur[t] = bhd[b * NB + t];
        __syncthreads();
        int beg, end;
        chunk_bounds(E, b, beg, end);
        int e = beg + threadIdx.x * 8;
        for (; e + 8 <= end; e += 2048) {
            int4 d0 = *(const int4*)&dst[e];
            int4 d1 = *(const int4*)&dst[e + 4];
            int4 s0 = *(const int4*)&src[e];
            int4 s1 = *(const int4*)&src[e + 4];
            int p0 = atomicAdd(&cur[d0.x >> BSH], 1); pairbuf[p0] = ((d0.x & 1023) << 17) | s0.x;
            int p1 = atomicAdd(&cur[d0.y >> BSH], 1); pairbuf[p1] = ((d0.y & 1023) << 17) | s0.y;
            int p2 = atomicAdd(&cur[d0.z >> BSH], 1); pairbuf[p2] = ((d0.z & 1023) << 17) | s0.z;
            int p3 = atomicAdd(&cur[d0.w >> BSH], 1); pairbuf[p3] = ((d0.w & 1023) << 17) | s0.w;
            int p4 = atomicAdd(&cur[d1.x >> BSH], 1); pairbuf[p4] = ((d1.x & 1023) << 17) | s1.x;
            int p5 = atomicAdd(&cur[d1.y >> BSH], 1); pairbuf[p5] = ((d1.y & 1023) << 17) | s1.y;
            int p6 = atomicAdd(&cur[d1.z >> BSH], 1); pairbuf[p6] = ((d1.z & 1023) << 17) | s1.z;
            int p7 = atomicAdd(&cur[d1.w >> BSH], 1); pairbuf[p7] = ((d1.w & 1023) << 17) | s1.w;
        }
        for (; e < end; ++e) {
            int d = dst[e], sv = src[e];
            int pd = atomicAdd(&cur[d >> BSH], 1);
            pairbuf[pd] = ((d & 1023) << 17) | sv;
        }
        return;
    }
    if ((int)blockIdx.x < 2 * NBLK2) {
        // ---------- src partition (8-edge unrolled) ----------
        int b = blockIdx.x - NBLK2;
        for (int t = threadIdx.x; t < NB; t += 256) cur[t] = bhs[b * NB + t];
        __syncthreads();
        int beg, end;
        chunk_bounds(E, b, beg, end);
        int e = beg + threadIdx.x * 8;
        for (; e + 8 <= end; e += 2048) {
            int4 s0 = *(const int4*)&src[e];
            int4 s1 = *(const int4*)&src[e + 4];
            int q0 = atomicAdd(&cur[s0.x >> BSH], 1); srctmp[q0] = s0.x;
            int q1 = atomicAdd(&cur[s0.y >> BSH], 1); srctmp[q1] = s0.y;
            int q2 = atomicAdd(&cur[s0.z >> BSH], 1); srctmp[q2] = s0.z;
            int q3 = atomicAdd(&cur[s0.w >> BSH], 1); srctmp[q3] = s0.w;
            int q4 = atomicAdd(&cur[s1.x >> BSH], 1); srctmp[q4] = s1.x;
            int q5 = atomicAdd(&cur[s1.y >> BSH], 1); srctmp[q5] = s1.y;
            int q6 = atomicAdd(&cur[s1.z >> BSH], 1); srctmp[q6] = s1.z;
            int q7 = atomicAdd(&cur[s1.w >> BSH], 1); srctmp[q7] = s1.w;
        }
        for (; e < end; ++e) {
            int sv = src[e];
            int ps = atomicAdd(&cur[sv >> BSH], 1);
            srctmp[ps] = sv;
        }
        return;
    }
    // ---------- layer-1 GEMM ----------
    const int tid = threadIdx.x;
    const int wave = tid >> 6, lane = tid & 63;
    const int g = lane >> 4, lm = lane & 15;
    const int gr0 = (blockIdx.x - 2 * NBLK2) * 64;

    floatx4 acc[4];
    #pragma unroll
    for (int f = 0; f < 4; ++f) acc[f] = (floatx4)0.f;

    for (int kc = 0; kc < IN_FEATS; kc += 64) {
        for (int c = tid; c < 64 * 8; c += 256) {
            int row = c >> 3, c8 = c & 7;
            int grow = gr0 + row;
            unsigned short v[8];
            if (grow < nrows) {
                const float* Xf = feat + (size_t)grow * IN_FEATS + kc + c8 * 8;
                #pragma unroll
                for (int j = 0; j < 8; ++j) v[j] = f2bf(Xf[j]);
            } else {
                #pragma unroll
                for (int j = 0; j < 8; ++j) v[j] = 0;
            }
            int off = (row * 64 + c8 * 8) ^ ((row & 7) << 3);
            *(uint4*)&Al[off] = *(uint4*)v;
        }
        for (int c = tid; c < 64 * 8; c += 256) {
            int col = c >> 3, c8 = c & 7;
            uint4 raw = *(const uint4*)&W1t[(size_t)col * IN_FEATS + kc + c8 * 8];
            int off = (col * 64 + c8 * 8) ^ ((col & 7) << 3);
            *(uint4*)&Bl[off] = raw;
        }
        __syncthreads();
        #pragma unroll
        for (int ks = 0; ks < 2; ++ks) {
            int arow = wave * 16 + lm;
            int aoff = (arow * 64 + ks * 32 + g * 8) ^ ((arow & 7) << 3);
            shortx8 afrag = *(shortx8*)&Al[aoff];
            #pragma unroll
            for (int f = 0; f < 4; ++f) {
                int col = f * 16 + lm;
                int boff = (col * 64 + ks * 32 + g * 8) ^ ((col & 7) << 3);
                shortx8 bfrag = *(shortx8*)&Bl[boff];
                acc[f] = __builtin_amdgcn_mfma_f32_16x16x32_bf16(afrag, bfrag, acc[f], 0, 0, 0);
            }
        }
        __syncthreads();
    }
    #pragma unroll
    for (int f = 0; f < 4; ++f) {
        #pragma unroll
        for (int r = 0; r < 4; ++r) {
            int grow = gr0 + wave * 16 + g * 4 + r;
            if (grow < nrows) outq[(size_t)grow * 64 + f * 16 + lm] = f2q(acc[f][r]);
        }
    }
}

// ---------------- P4c: per-bucket CSR build + degree isqrt (1024 threads/block) -----
__global__ __launch_bounds__(1024) void p4c(const int* __restrict__ pairbuf,
                                            const int* __restrict__ srctmp,
                                            const int* __restrict__ based,
                                            const int* __restrict__ bases,
                                            int* __restrict__ indptr, int* __restrict__ colbuf,
                                            float* __restrict__ di_isqrt, float* __restrict__ do_isqrt,
                                            int N, int E, int nbuck) {
    __shared__ int cnt[1024], lp[1024], s[1024];
    int t = threadIdx.x;
    if ((int)blockIdx.x >= nbuck) {
        int b = blockIdx.x - nbuck;
        int nbase = b << BSH;
        int nn = min(1024, N - nbase);
        cnt[t] = 0;
        __syncthreads();
        int eb = bases[b], ee = bases[b + 1];
        for (int e = eb + t; e < ee; e += 1024)
            atomicAdd(&cnt[srctmp[e] - nbase], 1);
        __syncthreads();
        if (t < nn) do_isqrt[nbase + t] = rsqrtf((float)max(cnt[t], 1));
        return;
    }
    int b = blockIdx.x;
    int nbase = b << BSH;
    int nn = min(1024, N - nbase);
    cnt[t] = 0;
    __syncthreads();
    int eb = based[b], ee = based[b + 1];
    for (int e = eb + t; e < ee; e += 1024)
        atomicAdd(&cnt[pairbuf[e] >> 17], 1);
    __syncthreads();
    int own = cnt[t];
    s[t] = own;
    __syncthreads();
    for (int off = 1; off < 1024; off <<= 1) {
        int v = (t >= off) ? s[t - off] : 0;
        __syncthreads();
        s[t] += v;
        __syncthreads();
    }
    lp[t] = s[t] - own;
    __syncthreads();
    if (t < nn) {
        indptr[nbase + t] = eb + lp[t];
        di_isqrt[nbase + t] = rsqrtf((float)max(own, 1));
    }
    if (b == 0 && t == 0) indptr[N] = E;
    __syncthreads();
    for (int e = eb + t; e < ee; e += 1024) {
        int pk = pairbuf[e];
        int pos = atomicAdd(&lp[pk >> 17], 1);
        colbuf[eb + pos] = pk & 0x1FFFF;
    }
}

// ---------------- MFMA GEMM (layers 2,3,P): single-stage full-K; OFP8 output --------
template <int COLS, int K, bool OFP8>
__global__ __launch_bounds__(256) void mgemm(
    const unsigned short* __restrict__ X, int ldx,
    const unsigned short* __restrict__ Wt,
    const float* __restrict__ rs,
    void* __restrict__ outv, int ldo, int nrows) {
    constexpr int NFRAG = COLS / 16;
    __shared__ unsigned short Al[64 * K];
    __shared__ unsigned short Bl[COLS * K];

    const int tid = threadIdx.x;
    const int wave = tid >> 6, lane = tid & 63;
    const int g = lane >> 4, lm = lane & 15;
    const int gr0 = blockIdx.x * 64;

    for (int c = tid; c < 64 * (K / 8); c += 256) {
        int row = c / (K / 8), c8 = c % (K / 8);
        int grow = gr0 + row;
        unsigned short v[8];
        if (grow < nrows) {
            uint4 raw = *(const uint4*)(X + (size_t)grow * ldx + c8 * 8);
            unsigned short* rp = (unsigned short*)&raw;
            if (rs) {
                float sc = rs[grow];
                #pragma unroll
                for (int j = 0; j < 8; ++j) v[j] = f2bf(bf2f(rp[j]) * sc);
            } else {
                #pragma unroll
                for (int j = 0; j < 8; ++j) v[j] = rp[j];
            }
        } else {
            #pragma unroll
            for (int j = 0; j < 8; ++j) v[j] = 0;
        }
        int off = (row * K + c8 * 8) ^ ((row & 7) << 3);
        *(uint4*)&Al[off] = *(uint4*)v;
    }
    for (int c = tid; c < COLS * (K / 8); c += 256) {
        int col = c / (K / 8), c8 = c % (K / 8);
        uint4 raw = *(const uint4*)&Wt[(size_t)col * K + c8 * 8];
        int off = (col * K + c8 * 8) ^ ((col & 7) << 3);
        *(uint4*)&Bl[off] = raw;
    }
    __syncthreads();

    floatx4 acc[NFRAG];
    #pragma unroll
    for (int f = 0; f < NFRAG; ++f) acc[f] = (floatx4)0.f;
    int arow = wave * 16 + lm;
    #pragma unroll
    for (int ks = 0; ks < K / 32; ++ks) {
        int aoff = (arow * K + ks * 32 + g * 8) ^ ((arow & 7) << 3);
        shortx8 afrag = *(shortx8*)&Al[aoff];
        #pragma unroll
        for (int f = 0; f < NFRAG; ++f) {
            int col = f * 16 + lm;
            int boff = (col * K + ks * 32 + g * 8) ^ ((col & 7) << 3);
            shortx8 bfrag = *(shortx8*)&Bl[boff];
            acc[f] = __builtin_amdgcn_mfma_f32_16x16x32_bf16(afrag, bfrag, acc[f], 0, 0, 0);
        }
    }
    #pragma unroll
    for (int f = 0; f < NFRAG; ++f) {
        #pragma unroll
        for (int r = 0; r < 4; ++r) {
            int grow = gr0 + wave * 16 + g * 4 + r;
            if (grow < nrows) {
                if (OFP8) {
                    ((unsigned char*)outv)[(size_t)grow * ldo + f * 16 + lm] = f2q(acc[f][r]);
                } else {
                    ((unsigned short*)outv)[(size_t)grow * ldo + f * 16 + lm] = f2bf(acc[f][r]);
                }
            }
        }
    }
}

// ---------------- gather (fp8 rows): 8 lanes/node, uint2 rows, int4 colbuf ----------
template <bool DOV>
__global__ __launch_bounds__(256) void gatherH(
    const int* __restrict__ indptr, const int* __restrict__ colbuf,
    const uint2* __restrict__ finq,           // fp8 [*, 8] uint2 rows (64 fp8)
    const float* __restrict__ dov,
    const float* __restrict__ di, const float* __restrict__ bias,
    uint4* __restrict__ hout, int ldh, int coff, int N) {
    int j = threadIdx.x & 7;
    int node = blockIdx.x * 32 + (threadIdx.x >> 3);
    if (node >= N) return;
    int beg = indptr[node], end = indptr[node + 1];
    float a[8] = {};
    int e = beg;
    for (; e + 4 <= end; e += 4) {
        int4 cc = *(const int4*)&colbuf[e];
        uint2 u0 = finq[(size_t)cc.x * 8 + j];
        uint2 u1 = finq[(size_t)cc.y * 8 + j];
        uint2 u2 = finq[(size_t)cc.z * 8 + j];
        uint2 u3 = finq[(size_t)cc.w * 8 + j];
        accq8(u0, a, DOV ? dov[cc.x] : 1.0f);
        accq8(u1, a, DOV ? dov[cc.y] : 1.0f);
        accq8(u2, a, DOV ? dov[cc.z] : 1.0f);
        accq8(u3, a, DOV ? dov[cc.w] : 1.0f);
    }
    for (; e < end; ++e) {
        int c = colbuf[e];
        accq8(finq[(size_t)c * 8 + j], a, DOV ? dov[c] : 1.0f);
    }
    float dval = di[node];
    float4 b0 = *(const float4*)&bias[j * 8];
    float4 b1 = *(const float4*)&bias[j * 8 + 4];
    float r[8];
    r[0] = fmaxf(a[0] * dval + b0.x, 0.f); r[1] = fmaxf(a[1] * dval + b0.y, 0.f);
    r[2] = fmaxf(a[2] * dval + b0.z, 0.f); r[3] = fmaxf(a[3] * dval + b0.w, 0.f);
    r[4] = fmaxf(a[4] * dval + b1.x, 0.f); r[5] = fmaxf(a[5] * dval + b1.y, 0.f);
    r[6] = fmaxf(a[6] * dval + b1.z, 0.f); r[7] = fmaxf(a[7] * dval + b1.w, 0.f);
    uint4 o;
    o.x = pack2(r[0], r[1]); o.y = pack2(r[2], r[3]);
    o.z = pack2(r[4], r[5]); o.w = pack2(r[6], r[7]);
    hout[(size_t)node * ldh + coff + j] = o;
}

// ---------------- final gather (P stays bf16) ----------------
__global__ __launch_bounds__(256) void final_gather(
    const int* __restrict__ indptr, const int* __restrict__ colbuf,
    const uint4* __restrict__ P4,
    const float* __restrict__ bm,
    float* __restrict__ out, int N) {
    int j = threadIdx.x & 3;
    int node = blockIdx.x * 64 + (threadIdx.x >> 2);
    if (node >= N) return;
    int beg = indptr[node], end = indptr[node + 1];
    float a[8] = {};
    int e = beg;
    for (; e + 4 <= end; e += 4) {
        int4 cc = *(const int4*)&colbuf[e];
        uint4 u0 = P4[(size_t)cc.x * 4 + j];
        uint4 u1 = P4[(size_t)cc.y * 4 + j];
        uint4 u2 = P4[(size_t)cc.z * 4 + j];
        uint4 u3 = P4[(size_t)cc.w * 4 + j];
        acc8(u0, a); acc8(u1, a); acc8(u2, a); acc8(u3, a);
    }
    for (; e < end; ++e) acc8(P4[(size_t)colbuf[e] * 4 + j], a);
    float4 b0 = *(const float4*)&bm[j * 8];
    float4 b1 = *(const float4*)&bm[j * 8 + 4];
    float4 o0 = make_float4(a[0] + b0.x, a[1] + b0.y, a[2] + b0.z, a[3] + b0.w);
    float4 o1 = make_float4(a[4] + b1.x, a[5] + b1.y, a[6] + b1.z, a[7] + b1.w);
    *(float4*)&out[(size_t)node * 32 + j * 8] = o0;
    *(float4*)&out[(size_t)node * 32 + j * 8 + 4] = o1;
}

// ---------------- launch ----------------
extern "C" void kernel_launch(void* const* d_in, const int* in_sizes, int n_in,
                              void* d_out, int out_size, void* d_ws, size_t ws_size,
                              hipStream_t stream) {
    const float* feat = (const float*)d_in[0];
    const int*   src  = (const int*)d_in[1];
    const int*   dst  = (const int*)d_in[2];
    const float* W1   = (const float*)d_in[3];
    const float* b1   = (const float*)d_in[4];
    const float* W2   = (const float*)d_in[5];
    const float* b2   = (const float*)d_in[6];
    const float* W3   = (const float*)d_in[7];
    const float* b3   = (const float*)d_in[8];
    const float* Wm   = (const float*)d_in[9];
    const float* bm   = (const float*)d_in[10];
    float* out = (float*)d_out;

    const int N = in_sizes[0] / IN_FEATS;   // 100000
    const int E = in_sizes[1];              // 1600000
    const int NBUCK = (N + 1023) >> BSH;    // 98

    char* wsp = (char*)d_ws;
    auto alloc = [&](size_t bytes) {
        void* p = (void*)wsp;
        wsp += ((bytes + 255) / 256) * 256;
        return p;
    };
    int*   indptr   = (int*)alloc((size_t)(N + 1) * 4);
    int*   colbuf   = (int*)alloc((size_t)E * 4);
    int*   bhd      = (int*)alloc((size_t)NBLK2 * NB * 4);
    int*   bhs      = (int*)alloc((size_t)NBLK2 * NB * 4);
    int*   totd     = (int*)alloc(NB * 4);
    int*   tots     = (int*)alloc(NB * 4);
    int*   based    = (int*)alloc((NB + 1) * 4);
    int*   bases    = (int*)alloc((NB + 1) * 4);
    float* do_isqrt = (float*)alloc((size_t)N * 4);
    float* di_isqrt = (float*)alloc((size_t)N * 4);
    unsigned short* W1t = (unsigned short*)alloc(256 * 64 * 2);
    unsigned short* W2t = (unsigned short*)alloc(64 * 64 * 2);
    unsigned short* W3t = (unsigned short*)alloc(64 * 64 * 2);
    unsigned short* Wmt = (unsigned short*)alloc(192 * 32 * 2);
    unsigned short* Hb  = (unsigned short*)alloc((size_t)N * JK * 2);
    int*   pairbuf  = (int*)alloc((size_t)E * 4);
    int*   srctmp   = (int*)alloc((size_t)E * 4);
    unsigned char* tmpq = (unsigned char*)alloc((size_t)N * HID);   // fp8 rows
    unsigned short* P   = (unsigned short*)alloc((size_t)N * OUTF * 2);

    const int GB = (N + 63) / 64;      // 1563
    const int GGB = (N + 31) / 32;     // 3125

    p1_hist<<<NBLK2, 256, 0, stream>>>(src, dst, E, bhd, bhs);
    p2a_tot<<<2 * NB + 120, 256, 0, stream>>>(bhd, bhs, totd, tots, NBLK2,
                                              W1, W2, W3, Wm, W1t, W2t, W3t, Wmt);
    p2b_scan<<<2, NB, 0, stream>>>(totd, tots, based, bases);
    p2c_off<<<2 * NB, 256, 0, stream>>>(bhd, bhs, based, bases, NBLK2);
    // overlapped: dst-partition + src-partition first (latency-bound, small set),
    // unscaled layer-1 GEMM fills the rest of the machine (BW-bound)
    p3m<<<2 * NBLK2 + GB, 256, 0, stream>>>(src, dst, E, bhd, bhs, pairbuf, srctmp,
                                            feat, W1t, tmpq, N);
    p4c<<<2 * NBUCK, 1024, 0, stream>>>(pairbuf, srctmp, based, bases, indptr, colbuf,
                                        di_isqrt, do_isqrt, N, E, NBUCK);

    // layer 1 gather applies deferred dov scale per edge: (dov.x)@W == dov.(x@W)
    gatherH<true><<<GGB, 256, 0, stream>>>(indptr, colbuf, (const uint2*)tmpq, do_isqrt,
                                           di_isqrt, b1, (uint4*)Hb, 24, 0, N);
    mgemm<HID, HID, true><<<GB, 256, 0, stream>>>(Hb, JK, W2t, do_isqrt, tmpq, HID, N);
    gatherH<false><<<GGB, 256, 0, stream>>>(indptr, colbuf, (const uint2*)tmpq, nullptr,
                                            di_isqrt, b2, (uint4*)Hb, 24, 8, N);
    mgemm<HID, HID, true><<<GB, 256, 0, stream>>>(Hb + HID, JK, W3t, do_isqrt, tmpq, HID, N);
    gatherH<false><<<GGB, 256, 0, stream>>>(indptr, colbuf, (const uint2*)tmpq, nullptr,
                                            di_isqrt, b3, (uint4*)Hb, 24, 16, N);
    mgemm<OUTF, JK, false><<<GB, 256, 0, stream>>>(Hb, JK, Wmt, nullptr, P, OUTF, N);
    final_gather<<<(N + 63) / 64, 256, 0, stream>>>(indptr, colbuf, (const uint4*)P, bm, out, N);
}

// Round 16
// 204.438 us; speedup vs baseline: 1.0091x; 1.0091x over previous
//
#include <hip/hip_runtime.h>
#include <hip/hip_fp8.h>

#define IN_FEATS 256
#define HID 64
#define OUTF 32
#define JK (3*HID)

#define NB    128   // bucket slots (used: 98)
#define BSH   10    // bucket covers 1024 nodes
#define NBLK2 256   // edge-chunk blocks for hist/scatter (R14 best config)
// NOTE: packed pairbuf assumes N <= 2^17 (src 17 bits, local dst 10 bits). N=100000.

typedef __attribute__((ext_vector_type(4))) float floatx4;
typedef __attribute__((ext_vector_type(8))) short shortx8;

__device__ inline unsigned short f2bf(float f) {
    unsigned u = __float_as_uint(f);
    unsigned r = (u + 0x7fffu + ((u >> 16) & 1u)) >> 16;
    return (unsigned short)r;
}
__device__ inline float bf2f(unsigned short u) {
    return __uint_as_float(((unsigned)u) << 16);
}
__device__ inline unsigned pack2(float a, float b) {
    return (unsigned)f2bf(a) | ((unsigned)f2bf(b) << 16);
}
// fp8 e4m3 (OCP on gfx950) helpers
__device__ inline unsigned char f2q(float f) {
    __hip_fp8_e4m3 q(f);
    return (unsigned char)q.__x;
}
__device__ inline float q2f(unsigned char b) {
    union { unsigned char c; __hip_fp8_e4m3 q; } u;
    u.c = b;
    return (float)u.q;
}
__device__ inline void accq8(uint2 u, float* a, float s) {
    a[0] = fmaf(q2f((unsigned char)(u.x      )), s, a[0]);
    a[1] = fmaf(q2f((unsigned char)(u.x >>  8)), s, a[1]);
    a[2] = fmaf(q2f((unsigned char)(u.x >> 16)), s, a[2]);
    a[3] = fmaf(q2f((unsigned char)(u.x >> 24)), s, a[3]);
    a[4] = fmaf(q2f((unsigned char)(u.y      )), s, a[4]);
    a[5] = fmaf(q2f((unsigned char)(u.y >>  8)), s, a[5]);
    a[6] = fmaf(q2f((unsigned char)(u.y >> 16)), s, a[6]);
    a[7] = fmaf(q2f((unsigned char)(u.y >> 24)), s, a[7]);
}
__device__ inline void acc8(uint4 u, float* a) {
    a[0] += bf2f((unsigned short)(u.x & 0xffff)); a[1] += bf2f((unsigned short)(u.x >> 16));
    a[2] += bf2f((unsigned short)(u.y & 0xffff)); a[3] += bf2f((unsigned short)(u.y >> 16));
    a[4] += bf2f((unsigned short)(u.z & 0xffff)); a[5] += bf2f((unsigned short)(u.z >> 16));
    a[6] += bf2f((unsigned short)(u.w & 0xffff)); a[7] += bf2f((unsigned short)(u.w >> 16));
}

// chunk bounds: cb multiple of 8 so int4-pair loads stay aligned from an aligned base
__device__ inline void chunk_bounds(int E, int b, int& beg, int& end) {
    int cb = ((E + NBLK2 - 1) / NBLK2 + 7) & ~7;
    beg = b * cb;
    end = min(beg + cb, E);
}

// ---------------- P1: per-block LDS histograms (8-edge unrolled) ----------------
__global__ __launch_bounds__(256) void p1_hist(const int* __restrict__ src,
                                               const int* __restrict__ dst, int E,
                                               int* __restrict__ bhd, int* __restrict__ bhs) {
    __shared__ int hd[NB], hs[NB];
    int b = blockIdx.x;
    for (int t = threadIdx.x; t < NB; t += 256) { hd[t] = 0; hs[t] = 0; }
    __syncthreads();
    int beg, end;
    chunk_bounds(E, b, beg, end);
    int e = beg + threadIdx.x * 8;
    for (; e + 8 <= end; e += 2048) {
        int4 d0 = *(const int4*)&dst[e];
        int4 d1 = *(const int4*)&dst[e + 4];
        int4 s0 = *(const int4*)&src[e];
        int4 s1 = *(const int4*)&src[e + 4];
        atomicAdd(&hd[d0.x >> BSH], 1); atomicAdd(&hd[d0.y >> BSH], 1);
        atomicAdd(&hd[d0.z >> BSH], 1); atomicAdd(&hd[d0.w >> BSH], 1);
        atomicAdd(&hd[d1.x >> BSH], 1); atomicAdd(&hd[d1.y >> BSH], 1);
        atomicAdd(&hd[d1.z >> BSH], 1); atomicAdd(&hd[d1.w >> BSH], 1);
        atomicAdd(&hs[s0.x >> BSH], 1); atomicAdd(&hs[s0.y >> BSH], 1);
        atomicAdd(&hs[s0.z >> BSH], 1); atomicAdd(&hs[s0.w >> BSH], 1);
        atomicAdd(&hs[s1.x >> BSH], 1); atomicAdd(&hs[s1.y >> BSH], 1);
        atomicAdd(&hs[s1.z >> BSH], 1); atomicAdd(&hs[s1.w >> BSH], 1);
    }
    for (; e < end; ++e) {
        atomicAdd(&hd[dst[e] >> BSH], 1);
        atomicAdd(&hs[src[e] >> BSH], 1);
    }
    __syncthreads();
    for (int t = threadIdx.x; t < NB; t += 256) {
        bhd[b * NB + t] = hd[t];
        bhs[b * NB + t] = hs[t];
    }
}

// ---------------- P2a (+wprep grid-fused) ----------------
__global__ __launch_bounds__(256) void p2a_tot(const int* __restrict__ bhd,
                                               const int* __restrict__ bhs,
                                               int* __restrict__ totd, int* __restrict__ tots,
                                               int nblk,
                                               const float* __restrict__ W1, const float* __restrict__ W2,
                                               const float* __restrict__ W3, const float* __restrict__ Wm,
                                               unsigned short* __restrict__ W1t, unsigned short* __restrict__ W2t,
                                               unsigned short* __restrict__ W3t, unsigned short* __restrict__ Wmt) {
    if ((int)blockIdx.x >= 2 * NB) {
        int i = (blockIdx.x - 2 * NB) * 256 + threadIdx.x;
        if (i < 256 * 64) { int k = i / 64, c = i % 64; W1t[c * 256 + k] = f2bf(W1[i]); return; }
        int j = i - 256 * 64;
        if (j < 64 * 64) { int k = j / 64, c = j % 64; W2t[c * 64 + k] = f2bf(W2[j]); return; }
        int j2 = j - 64 * 64;
        if (j2 < 64 * 64) { int k = j2 / 64, c = j2 % 64; W3t[c * 64 + k] = f2bf(W3[j2]); return; }
        int j3 = j2 - 64 * 64;
        if (j3 < 192 * 32) { int k = j3 / 32, c = j3 % 32; Wmt[c * 192 + k] = f2bf(Wm[j3]); }
        return;
    }
    __shared__ int s[256];
    int side = blockIdx.x >> 7;
    int t = blockIdx.x & (NB - 1);
    const int* bh = side ? bhs : bhd;
    int acc = 0;
    for (int k = threadIdx.x; k < nblk; k += 256) acc += bh[k * NB + t];
    s[threadIdx.x] = acc;
    __syncthreads();
    for (int off = 128; off > 0; off >>= 1) {
        if (threadIdx.x < off) s[threadIdx.x] += s[threadIdx.x + off];
        __syncthreads();
    }
    if (threadIdx.x == 0) (side ? tots : totd)[t] = s[0];
}

// ---------------- P2b: exclusive scan over NB bucket totals ----------------
__global__ __launch_bounds__(128) void p2b_scan(const int* __restrict__ totd,
                                                const int* __restrict__ tots,
                                                int* __restrict__ based, int* __restrict__ bases) {
    __shared__ int s[NB];
    const int* tot = blockIdx.x ? tots : totd;
    int* bb = blockIdx.x ? bases : based;
    int t = threadIdx.x;
    int v = tot[t];
    s[t] = v;
    __syncthreads();
    for (int off = 1; off < NB; off <<= 1) {
        int u = (t >= off) ? s[t - off] : 0;
        __syncthreads();
        s[t] += u;
        __syncthreads();
    }
    bb[t] = s[t] - v;
    if (t == NB - 1) bb[NB] = s[NB - 1];
}

// ---------------- P2c: per-bucket prefix over blocks (in place) ----------------
__global__ __launch_bounds__(256) void p2c_off(int* __restrict__ bhd, int* __restrict__ bhs,
                                               const int* __restrict__ based,
                                               const int* __restrict__ bases, int nblk) {
    __shared__ int s[256];
    int side = blockIdx.x >> 7;
    int t = blockIdx.x & (NB - 1);
    int* bh = side ? bhs : bhd;
    int carry = (side ? bases : based)[t];
    for (int k0 = 0; k0 < nblk; k0 += 256) {
        int k = k0 + threadIdx.x;
        int v = (k < nblk) ? bh[k * NB + t] : 0;
        s[threadIdx.x] = v;
        __syncthreads();
        for (int off = 1; off < 256; off <<= 1) {
            int u = (threadIdx.x >= off) ? s[threadIdx.x - off] : 0;
            __syncthreads();
            s[threadIdx.x] += u;
            __syncthreads();
        }
        if (k < nblk) bh[k * NB + t] = carry + s[threadIdx.x] - v;
        int tot = s[255];
        __syncthreads();
        carry += tot;
    }
}

// ---------------- P3M: grid-fused {dst-scatter} + {src-scatter} + {layer-1 GEMM} ----
// Scatter blocks FIRST (R13 lesson). GEMM A-staging uses explicit float4 loads:
// feat rows are 256 floats, offsets multiples of 8 floats -> 32B-aligned (provable),
// compiler cannot prove this from float* alone (G13) and was emitting scalar loads.
__global__ __launch_bounds__(256) void p3m(
    const int* __restrict__ src, const int* __restrict__ dst, int E,
    const int* __restrict__ bhd, const int* __restrict__ bhs,
    int* __restrict__ pairbuf, int* __restrict__ srctmp,
    const float* __restrict__ feat, const unsigned short* __restrict__ W1t,
    unsigned char* __restrict__ outq, int nrows) {
    __shared__ int cur[NB];
    __shared__ unsigned short Al[64 * 64];
    __shared__ unsigned short Bl[64 * 64];

    if ((int)blockIdx.x < NBLK2) {
        // ---------- dst-pair partition (8-edge unrolled) ----------
        int b = blockIdx.x;
        for (int t = threadIdx.x; t < NB; t += 256) cur[t] = bhd[b * NB + t];
        __syncthreads();
        int beg, end;
        chunk_bounds(E, b, beg, end);
        int e = beg + threadIdx.x * 8;
        for (; e + 8 <= end; e += 2048) {
            int4 d0 = *(const int4*)&dst[e];
            int4 d1 = *(const int4*)&dst[e + 4];
            int4 s0 = *(const int4*)&src[e];
            int4 s1 = *(const int4*)&src[e + 4];
            int p0 = atomicAdd(&cur[d0.x >> BSH], 1); pairbuf[p0] = ((d0.x & 1023) << 17) | s0.x;
            int p1 = atomicAdd(&cur[d0.y >> BSH], 1); pairbuf[p1] = ((d0.y & 1023) << 17) | s0.y;
            int p2 = atomicAdd(&cur[d0.z >> BSH], 1); pairbuf[p2] = ((d0.z & 1023) << 17) | s0.z;
            int p3 = atomicAdd(&cur[d0.w >> BSH], 1); pairbuf[p3] = ((d0.w & 1023) << 17) | s0.w;
            int p4 = atomicAdd(&cur[d1.x >> BSH], 1); pairbuf[p4] = ((d1.x & 1023) << 17) | s1.x;
            int p5 = atomicAdd(&cur[d1.y >> BSH], 1); pairbuf[p5] = ((d1.y & 1023) << 17) | s1.y;
            int p6 = atomicAdd(&cur[d1.z >> BSH], 1); pairbuf[p6] = ((d1.z & 1023) << 17) | s1.z;
            int p7 = atomicAdd(&cur[d1.w >> BSH], 1); pairbuf[p7] = ((d1.w & 1023) << 17) | s1.w;
        }
        for (; e < end; ++e) {
            int d = dst[e], sv = src[e];
            int pd = atomicAdd(&cur[d >> BSH], 1);
            pairbuf[pd] = ((d & 1023) << 17) | sv;
        }
        return;
    }
    if ((int)blockIdx.x < 2 * NBLK2) {
        // ---------- src partition (8-edge unrolled) ----------
        int b = blockIdx.x - NBLK2;
        for (int t = threadIdx.x; t < NB; t += 256) cur[t] = bhs[b * NB + t];
        __syncthreads();
        int beg, end;
        chunk_bounds(E, b, beg, end);
        int e = beg + threadIdx.x * 8;
        for (; e + 8 <= end; e += 2048) {
            int4 s0 = *(const int4*)&src[e];
            int4 s1 = *(const int4*)&src[e + 4];
            int q0 = atomicAdd(&cur[s0.x >> BSH], 1); srctmp[q0] = s0.x;
            int q1 = atomicAdd(&cur[s0.y >> BSH], 1); srctmp[q1] = s0.y;
            int q2 = atomicAdd(&cur[s0.z >> BSH], 1); srctmp[q2] = s0.z;
            int q3 = atomicAdd(&cur[s0.w >> BSH], 1); srctmp[q3] = s0.w;
            int q4 = atomicAdd(&cur[s1.x >> BSH], 1); srctmp[q4] = s1.x;
            int q5 = atomicAdd(&cur[s1.y >> BSH], 1); srctmp[q5] = s1.y;
            int q6 = atomicAdd(&cur[s1.z >> BSH], 1); srctmp[q6] = s1.z;
            int q7 = atomicAdd(&cur[s1.w >> BSH], 1); srctmp[q7] = s1.w;
        }
        for (; e < end; ++e) {
            int sv = src[e];
            int ps = atomicAdd(&cur[sv >> BSH], 1);
            srctmp[ps] = sv;
        }
        return;
    }
    // ---------- layer-1 GEMM (float4-vectorized feat staging) ----------
    const int tid = threadIdx.x;
    const int wave = tid >> 6, lane = tid & 63;
    const int g = lane >> 4, lm = lane & 15;
    const int gr0 = (blockIdx.x - 2 * NBLK2) * 64;

    floatx4 acc[4];
    #pragma unroll
    for (int f = 0; f < 4; ++f) acc[f] = (floatx4)0.f;

    for (int kc = 0; kc < IN_FEATS; kc += 64) {
        for (int c = tid; c < 64 * 8; c += 256) {
            int row = c >> 3, c8 = c & 7;
            int grow = gr0 + row;
            unsigned short v[8];
            if (grow < nrows) {
                const float* Xf = feat + (size_t)grow * IN_FEATS + kc + c8 * 8;
                float4 x0 = *(const float4*)Xf;
                float4 x1 = *(const float4*)(Xf + 4);
                v[0] = f2bf(x0.x); v[1] = f2bf(x0.y); v[2] = f2bf(x0.z); v[3] = f2bf(x0.w);
                v[4] = f2bf(x1.x); v[5] = f2bf(x1.y); v[6] = f2bf(x1.z); v[7] = f2bf(x1.w);
            } else {
                #pragma unroll
                for (int j = 0; j < 8; ++j) v[j] = 0;
            }
            int off = (row * 64 + c8 * 8) ^ ((row & 7) << 3);
            *(uint4*)&Al[off] = *(uint4*)v;
        }
        for (int c = tid; c < 64 * 8; c += 256) {
            int col = c >> 3, c8 = c & 7;
            uint4 raw = *(const uint4*)&W1t[(size_t)col * IN_FEATS + kc + c8 * 8];
            int off = (col * 64 + c8 * 8) ^ ((col & 7) << 3);
            *(uint4*)&Bl[off] = raw;
        }
        __syncthreads();
        #pragma unroll
        for (int ks = 0; ks < 2; ++ks) {
            int arow = wave * 16 + lm;
            int aoff = (arow * 64 + ks * 32 + g * 8) ^ ((arow & 7) << 3);
            shortx8 afrag = *(shortx8*)&Al[aoff];
            #pragma unroll
            for (int f = 0; f < 4; ++f) {
                int col = f * 16 + lm;
                int boff = (col * 64 + ks * 32 + g * 8) ^ ((col & 7) << 3);
                shortx8 bfrag = *(shortx8*)&Bl[boff];
                acc[f] = __builtin_amdgcn_mfma_f32_16x16x32_bf16(afrag, bfrag, acc[f], 0, 0, 0);
            }
        }
        __syncthreads();
    }
    #pragma unroll
    for (int f = 0; f < 4; ++f) {
        #pragma unroll
        for (int r = 0; r < 4; ++r) {
            int grow = gr0 + wave * 16 + g * 4 + r;
            if (grow < nrows) outq[(size_t)grow * 64 + f * 16 + lm] = f2q(acc[f][r]);
        }
    }
}

// ---------------- P4c: per-bucket CSR build + degree isqrt (1024 threads/block) -----
__global__ __launch_bounds__(1024) void p4c(const int* __restrict__ pairbuf,
                                            const int* __restrict__ srctmp,
                                            const int* __restrict__ based,
                                            const int* __restrict__ bases,
                                            int* __restrict__ indptr, int* __restrict__ colbuf,
                                            float* __restrict__ di_isqrt, float* __restrict__ do_isqrt,
                                            int N, int E, int nbuck) {
    __shared__ int cnt[1024], lp[1024], s[1024];
    int t = threadIdx.x;
    if ((int)blockIdx.x >= nbuck) {
        int b = blockIdx.x - nbuck;
        int nbase = b << BSH;
        int nn = min(1024, N - nbase);
        cnt[t] = 0;
        __syncthreads();
        int eb = bases[b], ee = bases[b + 1];
        for (int e = eb + t; e < ee; e += 1024)
            atomicAdd(&cnt[srctmp[e] - nbase], 1);
        __syncthreads();
        if (t < nn) do_isqrt[nbase + t] = rsqrtf((float)max(cnt[t], 1));
        return;
    }
    int b = blockIdx.x;
    int nbase = b << BSH;
    int nn = min(1024, N - nbase);
    cnt[t] = 0;
    __syncthreads();
    int eb = based[b], ee = based[b + 1];
    for (int e = eb + t; e < ee; e += 1024)
        atomicAdd(&cnt[pairbuf[e] >> 17], 1);
    __syncthreads();
    int own = cnt[t];
    s[t] = own;
    __syncthreads();
    for (int off = 1; off < 1024; off <<= 1) {
        int v = (t >= off) ? s[t - off] : 0;
        __syncthreads();
        s[t] += v;
        __syncthreads();
    }
    lp[t] = s[t] - own;
    __syncthreads();
    if (t < nn) {
        indptr[nbase + t] = eb + lp[t];
        di_isqrt[nbase + t] = rsqrtf((float)max(own, 1));
    }
    if (b == 0 && t == 0) indptr[N] = E;
    __syncthreads();
    for (int e = eb + t; e < ee; e += 1024) {
        int pk = pairbuf[e];
        int pos = atomicAdd(&lp[pk >> 17], 1);
        colbuf[eb + pos] = pk & 0x1FFFF;
    }
}

// ---------------- MFMA GEMM (layers 2,3,P): single-stage full-K; OFP8 output --------
template <int COLS, int K, bool OFP8>
__global__ __launch_bounds__(256) void mgemm(
    const unsigned short* __restrict__ X, int ldx,
    const unsigned short* __restrict__ Wt,
    const float* __restrict__ rs,
    void* __restrict__ outv, int ldo, int nrows) {
    constexpr int NFRAG = COLS / 16;
    __shared__ unsigned short Al[64 * K];
    __shared__ unsigned short Bl[COLS * K];

    const int tid = threadIdx.x;
    const int wave = tid >> 6, lane = tid & 63;
    const int g = lane >> 4, lm = lane & 15;
    const int gr0 = blockIdx.x * 64;

    for (int c = tid; c < 64 * (K / 8); c += 256) {
        int row = c / (K / 8), c8 = c % (K / 8);
        int grow = gr0 + row;
        unsigned short v[8];
        if (grow < nrows) {
            uint4 raw = *(const uint4*)(X + (size_t)grow * ldx + c8 * 8);
            unsigned short* rp = (unsigned short*)&raw;
            if (rs) {
                float sc = rs[grow];
                #pragma unroll
                for (int j = 0; j < 8; ++j) v[j] = f2bf(bf2f(rp[j]) * sc);
            } else {
                #pragma unroll
                for (int j = 0; j < 8; ++j) v[j] = rp[j];
            }
        } else {
            #pragma unroll
            for (int j = 0; j < 8; ++j) v[j] = 0;
        }
        int off = (row * K + c8 * 8) ^ ((row & 7) << 3);
        *(uint4*)&Al[off] = *(uint4*)v;
    }
    for (int c = tid; c < COLS * (K / 8); c += 256) {
        int col = c / (K / 8), c8 = c % (K / 8);
        uint4 raw = *(const uint4*)&Wt[(size_t)col * K + c8 * 8];
        int off = (col * K + c8 * 8) ^ ((col & 7) << 3);
        *(uint4*)&Bl[off] = raw;
    }
    __syncthreads();

    floatx4 acc[NFRAG];
    #pragma unroll
    for (int f = 0; f < NFRAG; ++f) acc[f] = (floatx4)0.f;
    int arow = wave * 16 + lm;
    #pragma unroll
    for (int ks = 0; ks < K / 32; ++ks) {
        int aoff = (arow * K + ks * 32 + g * 8) ^ ((arow & 7) << 3);
        shortx8 afrag = *(shortx8*)&Al[aoff];
        #pragma unroll
        for (int f = 0; f < NFRAG; ++f) {
            int col = f * 16 + lm;
            int boff = (col * K + ks * 32 + g * 8) ^ ((col & 7) << 3);
            shortx8 bfrag = *(shortx8*)&Bl[boff];
            acc[f] = __builtin_amdgcn_mfma_f32_16x16x32_bf16(afrag, bfrag, acc[f], 0, 0, 0);
        }
    }
    #pragma unroll
    for (int f = 0; f < NFRAG; ++f) {
        #pragma unroll
        for (int r = 0; r < 4; ++r) {
            int grow = gr0 + wave * 16 + g * 4 + r;
            if (grow < nrows) {
                if (OFP8) {
                    ((unsigned char*)outv)[(size_t)grow * ldo + f * 16 + lm] = f2q(acc[f][r]);
                } else {
                    ((unsigned short*)outv)[(size_t)grow * ldo + f * 16 + lm] = f2bf(acc[f][r]);
                }
            }
        }
    }
}

// ---------------- gather (fp8 rows): 8 lanes/node, uint2 rows, int4 colbuf ----------
template <bool DOV>
__global__ __launch_bounds__(256) void gatherH(
    const int* __restrict__ indptr, const int* __restrict__ colbuf,
    const uint2* __restrict__ finq,           // fp8 [*, 8] uint2 rows (64 fp8)
    const float* __restrict__ dov,
    const float* __restrict__ di, const float* __restrict__ bias,
    uint4* __restrict__ hout, int ldh, int coff, int N) {
    int j = threadIdx.x & 7;
    int node = blockIdx.x * 32 + (threadIdx.x >> 3);
    if (node >= N) return;
    int beg = indptr[node], end = indptr[node + 1];
    float a[8] = {};
    int e = beg;
    for (; e + 4 <= end; e += 4) {
        int4 cc = *(const int4*)&colbuf[e];
        uint2 u0 = finq[(size_t)cc.x * 8 + j];
        uint2 u1 = finq[(size_t)cc.y * 8 + j];
        uint2 u2 = finq[(size_t)cc.z * 8 + j];
        uint2 u3 = finq[(size_t)cc.w * 8 + j];
        accq8(u0, a, DOV ? dov[cc.x] : 1.0f);
        accq8(u1, a, DOV ? dov[cc.y] : 1.0f);
        accq8(u2, a, DOV ? dov[cc.z] : 1.0f);
        accq8(u3, a, DOV ? dov[cc.w] : 1.0f);
    }
    for (; e < end; ++e) {
        int c = colbuf[e];
        accq8(finq[(size_t)c * 8 + j], a, DOV ? dov[c] : 1.0f);
    }
    float dval = di[node];
    float4 b0 = *(const float4*)&bias[j * 8];
    float4 b1 = *(const float4*)&bias[j * 8 + 4];
    float r[8];
    r[0] = fmaxf(a[0] * dval + b0.x, 0.f); r[1] = fmaxf(a[1] * dval + b0.y, 0.f);
    r[2] = fmaxf(a[2] * dval + b0.z, 0.f); r[3] = fmaxf(a[3] * dval + b0.w, 0.f);
    r[4] = fmaxf(a[4] * dval + b1.x, 0.f); r[5] = fmaxf(a[5] * dval + b1.y, 0.f);
    r[6] = fmaxf(a[6] * dval + b1.z, 0.f); r[7] = fmaxf(a[7] * dval + b1.w, 0.f);
    uint4 o;
    o.x = pack2(r[0], r[1]); o.y = pack2(r[2], r[3]);
    o.z = pack2(r[4], r[5]); o.w = pack2(r[6], r[7]);
    hout[(size_t)node * ldh + coff + j] = o;
}

// ---------------- final gather (P stays bf16) ----------------
__global__ __launch_bounds__(256) void final_gather(
    const int* __restrict__ indptr, const int* __restrict__ colbuf,
    const uint4* __restrict__ P4,
    const float* __restrict__ bm,
    float* __restrict__ out, int N) {
    int j = threadIdx.x & 3;
    int node = blockIdx.x * 64 + (threadIdx.x >> 2);
    if (node >= N) return;
    int beg = indptr[node], end = indptr[node + 1];
    float a[8] = {};
    int e = beg;
    for (; e + 4 <= end; e += 4) {
        int4 cc = *(const int4*)&colbuf[e];
        uint4 u0 = P4[(size_t)cc.x * 4 + j];
        uint4 u1 = P4[(size_t)cc.y * 4 + j];
        uint4 u2 = P4[(size_t)cc.z * 4 + j];
        uint4 u3 = P4[(size_t)cc.w * 4 + j];
        acc8(u0, a); acc8(u1, a); acc8(u2, a); acc8(u3, a);
    }
    for (; e < end; ++e) acc8(P4[(size_t)colbuf[e] * 4 + j], a);
    float4 b0 = *(const float4*)&bm[j * 8];
    float4 b1 = *(const float4*)&bm[j * 8 + 4];
    float4 o0 = make_float4(a[0] + b0.x, a[1] + b0.y, a[2] + b0.z, a[3] + b0.w);
    float4 o1 = make_float4(a[4] + b1.x, a[5] + b1.y, a[6] + b1.z, a[7] + b1.w);
    *(float4*)&out[(size_t)node * 32 + j * 8] = o0;
    *(float4*)&out[(size_t)node * 32 + j * 8 + 4] = o1;
}

// ---------------- launch ----------------
extern "C" void kernel_launch(void* const* d_in, const int* in_sizes, int n_in,
                              void* d_out, int out_size, void* d_ws, size_t ws_size,
                              hipStream_t stream) {
    const float* feat = (const float*)d_in[0];
    const int*   src  = (const int*)d_in[1];
    const int*   dst  = (const int*)d_in[2];
    const float* W1   = (const float*)d_in[3];
    const float* b1   = (const float*)d_in[4];
    const float* W2   = (const float*)d_in[5];
    const float* b2   = (const float*)d_in[6];
    const float* W3   = (const float*)d_in[7];
    const float* b3   = (const float*)d_in[8];
    const float* Wm   = (const float*)d_in[9];
    const float* bm   = (const float*)d_in[10];
    float* out = (float*)d_out;

    const int N = in_sizes[0] / IN_FEATS;   // 100000
    const int E = in_sizes[1];              // 1600000
    const int NBUCK = (N + 1023) >> BSH;    // 98

    char* wsp = (char*)d_ws;
    auto alloc = [&](size_t bytes) {
        void* p = (void*)wsp;
        wsp += ((bytes + 255) / 256) * 256;
        return p;
    };
    int*   indptr   = (int*)alloc((size_t)(N + 1) * 4);
    int*   colbuf   = (int*)alloc((size_t)E * 4);
    int*   bhd      = (int*)alloc((size_t)NBLK2 * NB * 4);
    int*   bhs      = (int*)alloc((size_t)NBLK2 * NB * 4);
    int*   totd     = (int*)alloc(NB * 4);
    int*   tots     = (int*)alloc(NB * 4);
    int*   based    = (int*)alloc((NB + 1) * 4);
    int*   bases    = (int*)alloc((NB + 1) * 4);
    float* do_isqrt = (float*)alloc((size_t)N * 4);
    float* di_isqrt = (float*)alloc((size_t)N * 4);
    unsigned short* W1t = (unsigned short*)alloc(256 * 64 * 2);
    unsigned short* W2t = (unsigned short*)alloc(64 * 64 * 2);
    unsigned short* W3t = (unsigned short*)alloc(64 * 64 * 2);
    unsigned short* Wmt = (unsigned short*)alloc(192 * 32 * 2);
    unsigned short* Hb  = (unsigned short*)alloc((size_t)N * JK * 2);
    int*   pairbuf  = (int*)alloc((size_t)E * 4);
    int*   srctmp   = (int*)alloc((size_t)E * 4);
    unsigned char* tmpq = (unsigned char*)alloc((size_t)N * HID);   // fp8 rows
    unsigned short* P   = (unsigned short*)alloc((size_t)N * OUTF * 2);

    const int GB = (N + 63) / 64;      // 1563
    const int GGB = (N + 31) / 32;     // 3125

    p1_hist<<<NBLK2, 256, 0, stream>>>(src, dst, E, bhd, bhs);
    p2a_tot<<<2 * NB + 120, 256, 0, stream>>>(bhd, bhs, totd, tots, NBLK2,
                                              W1, W2, W3, Wm, W1t, W2t, W3t, Wmt);
    p2b_scan<<<2, NB, 0, stream>>>(totd, tots, based, bases);
    p2c_off<<<2 * NB, 256, 0, stream>>>(bhd, bhs, based, bases, NBLK2);
    // overlapped: dst-partition + src-partition first (latency-bound, small set),
    // unscaled layer-1 GEMM fills the rest of the machine (BW-bound)
    p3m<<<2 * NBLK2 + GB, 256, 0, stream>>>(src, dst, E, bhd, bhs, pairbuf, srctmp,
                                            feat, W1t, tmpq, N);
    p4c<<<2 * NBUCK, 1024, 0, stream>>>(pairbuf, srctmp, based, bases, indptr, colbuf,
                                        di_isqrt, do_isqrt, N, E, NBUCK);

    // layer 1 gather applies deferred dov scale per edge: (dov.x)@W == dov.(x@W)
    gatherH<true><<<GGB, 256, 0, stream>>>(indptr, colbuf, (const uint2*)tmpq, do_isqrt,
                                           di_isqrt, b1, (uint4*)Hb, 24, 0, N);
    mgemm<HID, HID, true><<<GB, 256, 0, stream>>>(Hb, JK, W2t, do_isqrt, tmpq, HID, N);
    gatherH<false><<<GGB, 256, 0, stream>>>(indptr, colbuf, (const uint2*)tmpq, nullptr,
                                            di_isqrt, b2, (uint4*)Hb, 24, 8, N);
    mgemm<HID, HID, true><<<GB, 256, 0, stream>>>(Hb + HID, JK, W3t, do_isqrt, tmpq, HID, N);
    gatherH<false><<<GGB, 256, 0, stream>>>(indptr, colbuf, (const uint2*)tmpq, nullptr,
                                            di_isqrt, b3, (uint4*)Hb, 24, 16, N);
    mgemm<OUTF, JK, false><<<GB, 256, 0, stream>>>(Hb, JK, Wmt, nullptr, P, OUTF, N);
    final_gather<<<(N + 63) / 64, 256, 0, stream>>>(indptr, colbuf, (const uint4*)P, bm, out, N);
}

// Round 17
// 202.718 us; speedup vs baseline: 1.0176x; 1.0085x over previous
//
#include <hip/hip_runtime.h>
#include <hip/hip_fp8.h>

#define IN_FEATS 256
#define HID 64
#define OUTF 32
#define JK (3*HID)

#define NB    128   // bucket slots (used: 98)
#define BSH   10    // bucket covers 1024 nodes
#define NBLK2 256   // edge-chunk blocks for hist/scatter (R14/R16 best config)
// NOTE: packed pairbuf assumes N <= 2^17 (src 17 bits, local dst 10 bits). N=100000.

typedef __attribute__((ext_vector_type(4))) float floatx4;
typedef __attribute__((ext_vector_type(8))) short shortx8;

__device__ inline unsigned short f2bf(float f) {
    unsigned u = __float_as_uint(f);
    unsigned r = (u + 0x7fffu + ((u >> 16) & 1u)) >> 16;
    return (unsigned short)r;
}
__device__ inline float bf2f(unsigned short u) {
    return __uint_as_float(((unsigned)u) << 16);
}
__device__ inline unsigned pack2(float a, float b) {
    return (unsigned)f2bf(a) | ((unsigned)f2bf(b) << 16);
}
// fp8 e4m3 (OCP on gfx950) helpers
__device__ inline unsigned char f2q(float f) {
    __hip_fp8_e4m3 q(f);
    return (unsigned char)q.__x;
}
__device__ inline float q2f(unsigned char b) {
    union { unsigned char c; __hip_fp8_e4m3 q; } u;
    u.c = b;
    return (float)u.q;
}
__device__ inline void accq8(uint2 u, float* a, float s) {
    a[0] = fmaf(q2f((unsigned char)(u.x      )), s, a[0]);
    a[1] = fmaf(q2f((unsigned char)(u.x >>  8)), s, a[1]);
    a[2] = fmaf(q2f((unsigned char)(u.x >> 16)), s, a[2]);
    a[3] = fmaf(q2f((unsigned char)(u.x >> 24)), s, a[3]);
    a[4] = fmaf(q2f((unsigned char)(u.y      )), s, a[4]);
    a[5] = fmaf(q2f((unsigned char)(u.y >>  8)), s, a[5]);
    a[6] = fmaf(q2f((unsigned char)(u.y >> 16)), s, a[6]);
    a[7] = fmaf(q2f((unsigned char)(u.y >> 24)), s, a[7]);
}
__device__ inline void acc8(uint4 u, float* a) {
    a[0] += bf2f((unsigned short)(u.x & 0xffff)); a[1] += bf2f((unsigned short)(u.x >> 16));
    a[2] += bf2f((unsigned short)(u.y & 0xffff)); a[3] += bf2f((unsigned short)(u.y >> 16));
    a[4] += bf2f((unsigned short)(u.z & 0xffff)); a[5] += bf2f((unsigned short)(u.z >> 16));
    a[6] += bf2f((unsigned short)(u.w & 0xffff)); a[7] += bf2f((unsigned short)(u.w >> 16));
}

// chunk bounds: cb multiple of 8 so int4-pair loads stay aligned from an aligned base
__device__ inline void chunk_bounds(int E, int b, int& beg, int& end) {
    int cb = ((E + NBLK2 - 1) / NBLK2 + 7) & ~7;
    beg = b * cb;
    end = min(beg + cb, E);
}

// ---------------- P1: per-block LDS histograms (8-edge unrolled) ----------------
__global__ __launch_bounds__(256) void p1_hist(const int* __restrict__ src,
                                               const int* __restrict__ dst, int E,
                                               int* __restrict__ bhd, int* __restrict__ bhs) {
    __shared__ int hd[NB], hs[NB];
    int b = blockIdx.x;
    for (int t = threadIdx.x; t < NB; t += 256) { hd[t] = 0; hs[t] = 0; }
    __syncthreads();
    int beg, end;
    chunk_bounds(E, b, beg, end);
    int e = beg + threadIdx.x * 8;
    for (; e + 8 <= end; e += 2048) {
        int4 d0 = *(const int4*)&dst[e];
        int4 d1 = *(const int4*)&dst[e + 4];
        int4 s0 = *(const int4*)&src[e];
        int4 s1 = *(const int4*)&src[e + 4];
        atomicAdd(&hd[d0.x >> BSH], 1); atomicAdd(&hd[d0.y >> BSH], 1);
        atomicAdd(&hd[d0.z >> BSH], 1); atomicAdd(&hd[d0.w >> BSH], 1);
        atomicAdd(&hd[d1.x >> BSH], 1); atomicAdd(&hd[d1.y >> BSH], 1);
        atomicAdd(&hd[d1.z >> BSH], 1); atomicAdd(&hd[d1.w >> BSH], 1);
        atomicAdd(&hs[s0.x >> BSH], 1); atomicAdd(&hs[s0.y >> BSH], 1);
        atomicAdd(&hs[s0.z >> BSH], 1); atomicAdd(&hs[s0.w >> BSH], 1);
        atomicAdd(&hs[s1.x >> BSH], 1); atomicAdd(&hs[s1.y >> BSH], 1);
        atomicAdd(&hs[s1.z >> BSH], 1); atomicAdd(&hs[s1.w >> BSH], 1);
    }
    for (; e < end; ++e) {
        atomicAdd(&hd[dst[e] >> BSH], 1);
        atomicAdd(&hs[src[e] >> BSH], 1);
    }
    __syncthreads();
    for (int t = threadIdx.x; t < NB; t += 256) {
        bhd[b * NB + t] = hd[t];
        bhs[b * NB + t] = hs[t];
    }
}

// ---------------- P2a (+wprep grid-fused) ----------------
__global__ __launch_bounds__(256) void p2a_tot(const int* __restrict__ bhd,
                                               const int* __restrict__ bhs,
                                               int* __restrict__ totd, int* __restrict__ tots,
                                               int nblk,
                                               const float* __restrict__ W1, const float* __restrict__ W2,
                                               const float* __restrict__ W3, const float* __restrict__ Wm,
                                               unsigned short* __restrict__ W1t, unsigned short* __restrict__ W2t,
                                               unsigned short* __restrict__ W3t, unsigned short* __restrict__ Wmt) {
    if ((int)blockIdx.x >= 2 * NB) {
        int i = (blockIdx.x - 2 * NB) * 256 + threadIdx.x;
        if (i < 256 * 64) { int k = i / 64, c = i % 64; W1t[c * 256 + k] = f2bf(W1[i]); return; }
        int j = i - 256 * 64;
        if (j < 64 * 64) { int k = j / 64, c = j % 64; W2t[c * 64 + k] = f2bf(W2[j]); return; }
        int j2 = j - 64 * 64;
        if (j2 < 64 * 64) { int k = j2 / 64, c = j2 % 64; W3t[c * 64 + k] = f2bf(W3[j2]); return; }
        int j3 = j2 - 64 * 64;
        if (j3 < 192 * 32) { int k = j3 / 32, c = j3 % 32; Wmt[c * 192 + k] = f2bf(Wm[j3]); }
        return;
    }
    __shared__ int s[256];
    int side = blockIdx.x >> 7;
    int t = blockIdx.x & (NB - 1);
    const int* bh = side ? bhs : bhd;
    int acc = 0;
    for (int k = threadIdx.x; k < nblk; k += 256) acc += bh[k * NB + t];
    s[threadIdx.x] = acc;
    __syncthreads();
    for (int off = 128; off > 0; off >>= 1) {
        if (threadIdx.x < off) s[threadIdx.x] += s[threadIdx.x + off];
        __syncthreads();
    }
    if (threadIdx.x == 0) (side ? tots : totd)[t] = s[0];
}

// ---------------- P2c: bucket-total scan (folded p2b) + per-bucket prefix over blocks
// Each block redundantly scans the 128 bucket totals in LDS (identical work, ~128 ops),
// derives its own carry, writes its slice of based/bases for p4c, then does the
// per-bucket prefix over the NBLK2 block-histogram entries (in place).
__global__ __launch_bounds__(256) void p2c_off(int* __restrict__ bhd, int* __restrict__ bhs,
                                               const int* __restrict__ totd,
                                               const int* __restrict__ tots,
                                               int* __restrict__ based, int* __restrict__ bases,
                                               int nblk) {
    __shared__ int s[256], ts[NB];
    int side = blockIdx.x >> 7;
    int t = blockIdx.x & (NB - 1);
    const int* tot = side ? tots : totd;
    int* bb = side ? bases : based;
    int* bh = side ? bhs : bhd;

    // ---- scan of 128 bucket totals (inclusive) ----
    int myv = 0;
    if (threadIdx.x < NB) { myv = tot[threadIdx.x]; ts[threadIdx.x] = myv; }
    __syncthreads();
    for (int off = 1; off < NB; off <<= 1) {
        int u = (threadIdx.x < NB && (int)threadIdx.x >= off) ? ts[threadIdx.x - off] : 0;
        __syncthreads();
        if (threadIdx.x < NB) ts[threadIdx.x] += u;
        __syncthreads();
    }
    // thread t writes this bucket's base; last bucket's block writes the sentinel
    if ((int)threadIdx.x == t) bb[t] = ts[t] - myv;
    if (t == NB - 1 && threadIdx.x == NB - 1) bb[NB] = ts[NB - 1];
    int carry = ts[t] - tot[t];     // exclusive prefix for this bucket

    // ---- per-bucket prefix over blocks (in place) ----
    for (int k0 = 0; k0 < nblk; k0 += 256) {
        int k = k0 + threadIdx.x;
        int v = (k < nblk) ? bh[k * NB + t] : 0;
        s[threadIdx.x] = v;
        __syncthreads();
        for (int off = 1; off < 256; off <<= 1) {
            int u = (threadIdx.x >= off) ? s[threadIdx.x - off] : 0;
            __syncthreads();
            s[threadIdx.x] += u;
            __syncthreads();
        }
        if (k < nblk) bh[k * NB + t] = carry + s[threadIdx.x] - v;
        int tt = s[255];
        __syncthreads();
        carry += tt;
    }
}

// ---------------- P3M: grid-fused {dst-scatter} + {src-scatter} + {layer-1 GEMM} ----
// Scatter blocks FIRST (R13 lesson). GEMM A-staging uses explicit float4 loads (G13).
__global__ __launch_bounds__(256) void p3m(
    const int* __restrict__ src, const int* __restrict__ dst, int E,
    const int* __restrict__ bhd, const int* __restrict__ bhs,
    int* __restrict__ pairbuf, int* __restrict__ srctmp,
    const float* __restrict__ feat, const unsigned short* __restrict__ W1t,
    unsigned char* __restrict__ outq, int nrows) {
    __shared__ int cur[NB];
    __shared__ unsigned short Al[64 * 64];
    __shared__ unsigned short Bl[64 * 64];

    if ((int)blockIdx.x < NBLK2) {
        // ---------- dst-pair partition (8-edge unrolled) ----------
        int b = blockIdx.x;
        for (int t = threadIdx.x; t < NB; t += 256) cur[t] = bhd[b * NB + t];
        __syncthreads();
        int beg, end;
        chunk_bounds(E, b, beg, end);
        int e = beg + threadIdx.x * 8;
        for (; e + 8 <= end; e += 2048) {
            int4 d0 = *(const int4*)&dst[e];
            int4 d1 = *(const int4*)&dst[e + 4];
            int4 s0 = *(const int4*)&src[e];
            int4 s1 = *(const int4*)&src[e + 4];
            int p0 = atomicAdd(&cur[d0.x >> BSH], 1); pairbuf[p0] = ((d0.x & 1023) << 17) | s0.x;
            int p1 = atomicAdd(&cur[d0.y >> BSH], 1); pairbuf[p1] = ((d0.y & 1023) << 17) | s0.y;
            int p2 = atomicAdd(&cur[d0.z >> BSH], 1); pairbuf[p2] = ((d0.z & 1023) << 17) | s0.z;
            int p3 = atomicAdd(&cur[d0.w >> BSH], 1); pairbuf[p3] = ((d0.w & 1023) << 17) | s0.w;
            int p4 = atomicAdd(&cur[d1.x >> BSH], 1); pairbuf[p4] = ((d1.x & 1023) << 17) | s1.x;
            int p5 = atomicAdd(&cur[d1.y >> BSH], 1); pairbuf[p5] = ((d1.y & 1023) << 17) | s1.y;
            int p6 = atomicAdd(&cur[d1.z >> BSH], 1); pairbuf[p6] = ((d1.z & 1023) << 17) | s1.z;
            int p7 = atomicAdd(&cur[d1.w >> BSH], 1); pairbuf[p7] = ((d1.w & 1023) << 17) | s1.w;
        }
        for (; e < end; ++e) {
            int d = dst[e], sv = src[e];
            int pd = atomicAdd(&cur[d >> BSH], 1);
            pairbuf[pd] = ((d & 1023) << 17) | sv;
        }
        return;
    }
    if ((int)blockIdx.x < 2 * NBLK2) {
        // ---------- src partition (8-edge unrolled) ----------
        int b = blockIdx.x - NBLK2;
        for (int t = threadIdx.x; t < NB; t += 256) cur[t] = bhs[b * NB + t];
        __syncthreads();
        int beg, end;
        chunk_bounds(E, b, beg, end);
        int e = beg + threadIdx.x * 8;
        for (; e + 8 <= end; e += 2048) {
            int4 s0 = *(const int4*)&src[e];
            int4 s1 = *(const int4*)&src[e + 4];
            int q0 = atomicAdd(&cur[s0.x >> BSH], 1); srctmp[q0] = s0.x;
            int q1 = atomicAdd(&cur[s0.y >> BSH], 1); srctmp[q1] = s0.y;
            int q2 = atomicAdd(&cur[s0.z >> BSH], 1); srctmp[q2] = s0.z;
            int q3 = atomicAdd(&cur[s0.w >> BSH], 1); srctmp[q3] = s0.w;
            int q4 = atomicAdd(&cur[s1.x >> BSH], 1); srctmp[q4] = s1.x;
            int q5 = atomicAdd(&cur[s1.y >> BSH], 1); srctmp[q5] = s1.y;
            int q6 = atomicAdd(&cur[s1.z >> BSH], 1); srctmp[q6] = s1.z;
            int q7 = atomicAdd(&cur[s1.w >> BSH], 1); srctmp[q7] = s1.w;
        }
        for (; e < end; ++e) {
            int sv = src[e];
            int ps = atomicAdd(&cur[sv >> BSH], 1);
            srctmp[ps] = sv;
        }
        return;
    }
    // ---------- layer-1 GEMM (float4-vectorized feat staging) ----------
    const int tid = threadIdx.x;
    const int wave = tid >> 6, lane = tid & 63;
    const int g = lane >> 4, lm = lane & 15;
    const int gr0 = (blockIdx.x - 2 * NBLK2) * 64;

    floatx4 acc[4];
    #pragma unroll
    for (int f = 0; f < 4; ++f) acc[f] = (floatx4)0.f;

    for (int kc = 0; kc < IN_FEATS; kc += 64) {
        for (int c = tid; c < 64 * 8; c += 256) {
            int row = c >> 3, c8 = c & 7;
            int grow = gr0 + row;
            unsigned short v[8];
            if (grow < nrows) {
                const float* Xf = feat + (size_t)grow * IN_FEATS + kc + c8 * 8;
                float4 x0 = *(const float4*)Xf;
                float4 x1 = *(const float4*)(Xf + 4);
                v[0] = f2bf(x0.x); v[1] = f2bf(x0.y); v[2] = f2bf(x0.z); v[3] = f2bf(x0.w);
                v[4] = f2bf(x1.x); v[5] = f2bf(x1.y); v[6] = f2bf(x1.z); v[7] = f2bf(x1.w);
            } else {
                #pragma unroll
                for (int j = 0; j < 8; ++j) v[j] = 0;
            }
            int off = (row * 64 + c8 * 8) ^ ((row & 7) << 3);
            *(uint4*)&Al[off] = *(uint4*)v;
        }
        for (int c = tid; c < 64 * 8; c += 256) {
            int col = c >> 3, c8 = c & 7;
            uint4 raw = *(const uint4*)&W1t[(size_t)col * IN_FEATS + kc + c8 * 8];
            int off = (col * 64 + c8 * 8) ^ ((col & 7) << 3);
            *(uint4*)&Bl[off] = raw;
        }
        __syncthreads();
        #pragma unroll
        for (int ks = 0; ks < 2; ++ks) {
            int arow = wave * 16 + lm;
            int aoff = (arow * 64 + ks * 32 + g * 8) ^ ((arow & 7) << 3);
            shortx8 afrag = *(shortx8*)&Al[aoff];
            #pragma unroll
            for (int f = 0; f < 4; ++f) {
                int col = f * 16 + lm;
                int boff = (col * 64 + ks * 32 + g * 8) ^ ((col & 7) << 3);
                shortx8 bfrag = *(shortx8*)&Bl[boff];
                acc[f] = __builtin_amdgcn_mfma_f32_16x16x32_bf16(afrag, bfrag, acc[f], 0, 0, 0);
            }
        }
        __syncthreads();
    }
    #pragma unroll
    for (int f = 0; f < 4; ++f) {
        #pragma unroll
        for (int r = 0; r < 4; ++r) {
            int grow = gr0 + wave * 16 + g * 4 + r;
            if (grow < nrows) outq[(size_t)grow * 64 + f * 16 + lm] = f2q(acc[f][r]);
        }
    }
}

// ---------------- P4c: per-bucket CSR build + degree isqrt (1024 threads/block) -----
__global__ __launch_bounds__(1024) void p4c(const int* __restrict__ pairbuf,
                                            const int* __restrict__ srctmp,
                                            const int* __restrict__ based,
                                            const int* __restrict__ bases,
                                            int* __restrict__ indptr, int* __restrict__ colbuf,
                                            float* __restrict__ di_isqrt, float* __restrict__ do_isqrt,
                                            int N, int E, int nbuck) {
    __shared__ int cnt[1024], lp[1024], s[1024];
    int t = threadIdx.x;
    if ((int)blockIdx.x >= nbuck) {
        int b = blockIdx.x - nbuck;
        int nbase = b << BSH;
        int nn = min(1024, N - nbase);
        cnt[t] = 0;
        __syncthreads();
        int eb = bases[b], ee = bases[b + 1];
        for (int e = eb + t; e < ee; e += 1024)
            atomicAdd(&cnt[srctmp[e] - nbase], 1);
        __syncthreads();
        if (t < nn) do_isqrt[nbase + t] = rsqrtf((float)max(cnt[t], 1));
        return;
    }
    int b = blockIdx.x;
    int nbase = b << BSH;
    int nn = min(1024, N - nbase);
    cnt[t] = 0;
    __syncthreads();
    int eb = based[b], ee = based[b + 1];
    for (int e = eb + t; e < ee; e += 1024)
        atomicAdd(&cnt[pairbuf[e] >> 17], 1);
    __syncthreads();
    int own = cnt[t];
    s[t] = own;
    __syncthreads();
    for (int off = 1; off < 1024; off <<= 1) {
        int v = (t >= off) ? s[t - off] : 0;
        __syncthreads();
        s[t] += v;
        __syncthreads();
    }
    lp[t] = s[t] - own;
    __syncthreads();
    if (t < nn) {
        indptr[nbase + t] = eb + lp[t];
        di_isqrt[nbase + t] = rsqrtf((float)max(own, 1));
    }
    if (b == 0 && t == 0) indptr[N] = E;
    __syncthreads();
    for (int e = eb + t; e < ee; e += 1024) {
        int pk = pairbuf[e];
        int pos = atomicAdd(&lp[pk >> 17], 1);
        colbuf[eb + pos] = pk & 0x1FFFF;
    }
}

// ---------------- MFMA GEMM (layers 2,3,P): single-stage full-K; OFP8 output --------
template <int COLS, int K, bool OFP8>
__global__ __launch_bounds__(256) void mgemm(
    const unsigned short* __restrict__ X, int ldx,
    const unsigned short* __restrict__ Wt,
    const float* __restrict__ rs,
    void* __restrict__ outv, int ldo, int nrows) {
    constexpr int NFRAG = COLS / 16;
    __shared__ unsigned short Al[64 * K];
    __shared__ unsigned short Bl[COLS * K];

    const int tid = threadIdx.x;
    const int wave = tid >> 6, lane = tid & 63;
    const int g = lane >> 4, lm = lane & 15;
    const int gr0 = blockIdx.x * 64;

    for (int c = tid; c < 64 * (K / 8); c += 256) {
        int row = c / (K / 8), c8 = c % (K / 8);
        int grow = gr0 + row;
        unsigned short v[8];
        if (grow < nrows) {
            uint4 raw = *(const uint4*)(X + (size_t)grow * ldx + c8 * 8);
            unsigned short* rp = (unsigned short*)&raw;
            if (rs) {
                float sc = rs[grow];
                #pragma unroll
                for (int j = 0; j < 8; ++j) v[j] = f2bf(bf2f(rp[j]) * sc);
            } else {
                #pragma unroll
                for (int j = 0; j < 8; ++j) v[j] = rp[j];
            }
        } else {
            #pragma unroll
            for (int j = 0; j < 8; ++j) v[j] = 0;
        }
        int off = (row * K + c8 * 8) ^ ((row & 7) << 3);
        *(uint4*)&Al[off] = *(uint4*)v;
    }
    for (int c = tid; c < COLS * (K / 8); c += 256) {
        int col = c / (K / 8), c8 = c % (K / 8);
        uint4 raw = *(const uint4*)&Wt[(size_t)col * K + c8 * 8];
        int off = (col * K + c8 * 8) ^ ((col & 7) << 3);
        *(uint4*)&Bl[off] = raw;
    }
    __syncthreads();

    floatx4 acc[NFRAG];
    #pragma unroll
    for (int f = 0; f < NFRAG; ++f) acc[f] = (floatx4)0.f;
    int arow = wave * 16 + lm;
    #pragma unroll
    for (int ks = 0; ks < K / 32; ++ks) {
        int aoff = (arow * K + ks * 32 + g * 8) ^ ((arow & 7) << 3);
        shortx8 afrag = *(shortx8*)&Al[aoff];
        #pragma unroll
        for (int f = 0; f < NFRAG; ++f) {
            int col = f * 16 + lm;
            int boff = (col * K + ks * 32 + g * 8) ^ ((col & 7) << 3);
            shortx8 bfrag = *(shortx8*)&Bl[boff];
            acc[f] = __builtin_amdgcn_mfma_f32_16x16x32_bf16(afrag, bfrag, acc[f], 0, 0, 0);
        }
    }
    #pragma unroll
    for (int f = 0; f < NFRAG; ++f) {
        #pragma unroll
        for (int r = 0; r < 4; ++r) {
            int grow = gr0 + wave * 16 + g * 4 + r;
            if (grow < nrows) {
                if (OFP8) {
                    ((unsigned char*)outv)[(size_t)grow * ldo + f * 16 + lm] = f2q(acc[f][r]);
                } else {
                    ((unsigned short*)outv)[(size_t)grow * ldo + f * 16 + lm] = f2bf(acc[f][r]);
                }
            }
        }
    }
}

// ---------------- gather (fp8 rows): 8 lanes/node, uint2 rows, int4 colbuf ----------
template <bool DOV>
__global__ __launch_bounds__(256) void gatherH(
    const int* __restrict__ indptr, const int* __restrict__ colbuf,
    const uint2* __restrict__ finq,           // fp8 [*, 8] uint2 rows (64 fp8)
    const float* __restrict__ dov,
    const float* __restrict__ di, const float* __restrict__ bias,
    uint4* __restrict__ hout, int ldh, int coff, int N) {
    int j = threadIdx.x & 7;
    int node = blockIdx.x * 32 + (threadIdx.x >> 3);
    if (node >= N) return;
    int beg = indptr[node], end = indptr[node + 1];
    float a[8] = {};
    int e = beg;
    for (; e + 4 <= end; e += 4) {
        int4 cc = *(const int4*)&colbuf[e];
        uint2 u0 = finq[(size_t)cc.x * 8 + j];
        uint2 u1 = finq[(size_t)cc.y * 8 + j];
        uint2 u2 = finq[(size_t)cc.z * 8 + j];
        uint2 u3 = finq[(size_t)cc.w * 8 + j];
        accq8(u0, a, DOV ? dov[cc.x] : 1.0f);
        accq8(u1, a, DOV ? dov[cc.y] : 1.0f);
        accq8(u2, a, DOV ? dov[cc.z] : 1.0f);
        accq8(u3, a, DOV ? dov[cc.w] : 1.0f);
    }
    for (; e < end; ++e) {
        int c = colbuf[e];
        accq8(finq[(size_t)c * 8 + j], a, DOV ? dov[c] : 1.0f);
    }
    float dval = di[node];
    float4 b0 = *(const float4*)&bias[j * 8];
    float4 b1 = *(const float4*)&bias[j * 8 + 4];
    float r[8];
    r[0] = fmaxf(a[0] * dval + b0.x, 0.f); r[1] = fmaxf(a[1] * dval + b0.y, 0.f);
    r[2] = fmaxf(a[2] * dval + b0.z, 0.f); r[3] = fmaxf(a[3] * dval + b0.w, 0.f);
    r[4] = fmaxf(a[4] * dval + b1.x, 0.f); r[5] = fmaxf(a[5] * dval + b1.y, 0.f);
    r[6] = fmaxf(a[6] * dval + b1.z, 0.f); r[7] = fmaxf(a[7] * dval + b1.w, 0.f);
    uint4 o;
    o.x = pack2(r[0], r[1]); o.y = pack2(r[2], r[3]);
    o.z = pack2(r[4], r[5]); o.w = pack2(r[6], r[7]);
    hout[(size_t)node * ldh + coff + j] = o;
}

// ---------------- final gather (P stays bf16) ----------------
__global__ __launch_bounds__(256) void final_gather(
    const int* __restrict__ indptr, const int* __restrict__ colbuf,
    const uint4* __restrict__ P4,
    const float* __restrict__ bm,
    float* __restrict__ out, int N) {
    int j = threadIdx.x & 3;
    int node = blockIdx.x * 64 + (threadIdx.x >> 2);
    if (node >= N) return;
    int beg = indptr[node], end = indptr[node + 1];
    float a[8] = {};
    int e = beg;
    for (; e + 4 <= end; e += 4) {
        int4 cc = *(const int4*)&colbuf[e];
        uint4 u0 = P4[(size_t)cc.x * 4 + j];
        uint4 u1 = P4[(size_t)cc.y * 4 + j];
        uint4 u2 = P4[(size_t)cc.z * 4 + j];
        uint4 u3 = P4[(size_t)cc.w * 4 + j];
        acc8(u0, a); acc8(u1, a); acc8(u2, a); acc8(u3, a);
    }
    for (; e < end; ++e) acc8(P4[(size_t)colbuf[e] * 4 + j], a);
    float4 b0 = *(const float4*)&bm[j * 8];
    float4 b1 = *(const float4*)&bm[j * 8 + 4];
    float4 o0 = make_float4(a[0] + b0.x, a[1] + b0.y, a[2] + b0.z, a[3] + b0.w);
    float4 o1 = make_float4(a[4] + b1.x, a[5] + b1.y, a[6] + b1.z, a[7] + b1.w);
    *(float4*)&out[(size_t)node * 32 + j * 8] = o0;
    *(float4*)&out[(size_t)node * 32 + j * 8 + 4] = o1;
}

// ---------------- launch ----------------
extern "C" void kernel_launch(void* const* d_in, const int* in_sizes, int n_in,
                              void* d_out, int out_size, void* d_ws, size_t ws_size,
                              hipStream_t stream) {
    const float* feat = (const float*)d_in[0];
    const int*   src  = (const int*)d_in[1];
    const int*   dst  = (const int*)d_in[2];
    const float* W1   = (const float*)d_in[3];
    const float* b1   = (const float*)d_in[4];
    const float* W2   = (const float*)d_in[5];
    const float* b2   = (const float*)d_in[6];
    const float* W3   = (const float*)d_in[7];
    const float* b3   = (const float*)d_in[8];
    const float* Wm   = (const float*)d_in[9];
    const float* bm   = (const float*)d_in[10];
    float* out = (float*)d_out;

    const int N = in_sizes[0] / IN_FEATS;   // 100000
    const int E = in_sizes[1];              // 1600000
    const int NBUCK = (N + 1023) >> BSH;    // 98

    char* wsp = (char*)d_ws;
    auto alloc = [&](size_t bytes) {
        void* p = (void*)wsp;
        wsp += ((bytes + 255) / 256) * 256;
        return p;
    };
    int*   indptr   = (int*)alloc((size_t)(N + 1) * 4);
    int*   colbuf   = (int*)alloc((size_t)E * 4);
    int*   bhd      = (int*)alloc((size_t)NBLK2 * NB * 4);
    int*   bhs      = (int*)alloc((size_t)NBLK2 * NB * 4);
    int*   totd     = (int*)alloc(NB * 4);
    int*   tots     = (int*)alloc(NB * 4);
    int*   based    = (int*)alloc((NB + 1) * 4);
    int*   bases    = (int*)alloc((NB + 1) * 4);
    float* do_isqrt = (float*)alloc((size_t)N * 4);
    float* di_isqrt = (float*)alloc((size_t)N * 4);
    unsigned short* W1t = (unsigned short*)alloc(256 * 64 * 2);
    unsigned short* W2t = (unsigned short*)alloc(64 * 64 * 2);
    unsigned short* W3t = (unsigned short*)alloc(64 * 64 * 2);
    unsigned short* Wmt = (unsigned short*)alloc(192 * 32 * 2);
    unsigned short* Hb  = (unsigned short*)alloc((size_t)N * JK * 2);
    int*   pairbuf  = (int*)alloc((size_t)E * 4);
    int*   srctmp   = (int*)alloc((size_t)E * 4);
    unsigned char* tmpq = (unsigned char*)alloc((size_t)N * HID);   // fp8 rows
    unsigned short* P   = (unsigned short*)alloc((size_t)N * OUTF * 2);

    const int GB = (N + 63) / 64;      // 1563
    const int GGB = (N + 31) / 32;     // 3125

    p1_hist<<<NBLK2, 256, 0, stream>>>(src, dst, E, bhd, bhs);
    p2a_tot<<<2 * NB + 120, 256, 0, stream>>>(bhd, bhs, totd, tots, NBLK2,
                                              W1, W2, W3, Wm, W1t, W2t, W3t, Wmt);
    // p2b folded into p2c: each block scans the 128 bucket totals locally and writes
    // its slice of based/bases (consumed by p4c)
    p2c_off<<<2 * NB, 256, 0, stream>>>(bhd, bhs, totd, tots, based, bases, NBLK2);
    // overlapped: dst-partition + src-partition first (latency-bound, small set),
    // unscaled layer-1 GEMM fills the rest of the machine (BW-bound)
    p3m<<<2 * NBLK2 + GB, 256, 0, stream>>>(src, dst, E, bhd, bhs, pairbuf, srctmp,
                                            feat, W1t, tmpq, N);
    p4c<<<2 * NBUCK, 1024, 0, stream>>>(pairbuf, srctmp, based, bases, indptr, colbuf,
                                        di_isqrt, do_isqrt, N, E, NBUCK);

    // layer 1 gather applies deferred dov scale per edge: (dov.x)@W == dov.(x@W)
    gatherH<true><<<GGB, 256, 0, stream>>>(indptr, colbuf, (const uint2*)tmpq, do_isqrt,
                                           di_isqrt, b1, (uint4*)Hb, 24, 0, N);
    mgemm<HID, HID, true><<<GB, 256, 0, stream>>>(Hb, JK, W2t, do_isqrt, tmpq, HID, N);
    gatherH<false><<<GGB, 256, 0, stream>>>(indptr, colbuf, (const uint2*)tmpq, nullptr,
                                            di_isqrt, b2, (uint4*)Hb, 24, 8, N);
    mgemm<HID, HID, true><<<GB, 256, 0, stream>>>(Hb + HID, JK, W3t, do_isqrt, tmpq, HID, N);
    gatherH<false><<<GGB, 256, 0, stream>>>(indptr, colbuf, (const uint2*)tmpq, nullptr,
                                            di_isqrt, b3, (uint4*)Hb, 24, 16, N);
    mgemm<OUTF, JK, false><<<GB, 256, 0, stream>>>(Hb, JK, Wmt, nullptr, P, OUTF, N);
    final_gather<<<(N + 63) / 64, 256, 0, stream>>>(indptr, colbuf, (const uint4*)P, bm, out, N);
}